// Round 8
// baseline (334.423 us; speedup 1.0000x reference)
//
#include <hip/hip_runtime.h>
#include <hip/hip_bf16.h>

// ---------- problem constants ----------
#define B_      16
#define C_IN    3
#define IMG     512
#define PATCH   16
#define C_FEAT  2048
#define N_CLS   18
#define KCELL   24
#define HF      32
#define P_      (HF*HF)        // 1024
#define KDIM    (C_IN*PATCH*PATCH) // 768
#define M_GEMM1 (B_*P_)        // 16384
#define EPS_    1e-6f

typedef __attribute__((ext_vector_type(8))) short bf16x8;
typedef __attribute__((ext_vector_type(4))) float f32x4;
typedef __attribute__((ext_vector_type(4))) unsigned short us4;
typedef __attribute__((ext_vector_type(8))) unsigned short us8;
typedef __attribute__((ext_vector_type(4))) float fl4;

#define DEVFN static __device__ __forceinline__

DEVFN unsigned short f2bf(float f) {  // RNE f32->bf16 (bit math)
  union { float f; unsigned u; } x; x.f = f;
  unsigned r = (x.u + 0x7fffu + ((x.u >> 16) & 1u)) >> 16;
  return (unsigned short)r;
}
DEVFN unsigned short f2bf_h(float f) {  // RNE via HW cvt (pairs into v_cvt_pk_bf16_f32)
  __hip_bfloat16 h = __float2bfloat16(f);
  return *reinterpret_cast<unsigned short*>(&h);
}
DEVFN float bf2f(unsigned short u) {
  union { unsigned u; float f; } x; x.u = ((unsigned)u) << 16;
  return x.f;
}
DEVFN f32x4 mfma16(bf16x8 a, bf16x8 b, f32x4 c) {
  return __builtin_amdgcn_mfma_f32_16x16x32_bf16(a, b, c, 0, 0, 0);
}
#define GLOAD16(gp, lp) __builtin_amdgcn_global_load_lds( \
    (const __attribute__((address_space(1))) unsigned int*)(gp), \
    (__attribute__((address_space(3))) unsigned int*)(lp), 16, 0, 0)

// ---------- ws layout (bytes) ----------
#define OFF_CFP   0u            // CFpart f32 [16][24][8][2048]  25,165,824
#define OFF_WB    25165824u     // Wb_bf16 [2048][768]            3,145,728
#define OFF_CF    100702208u    // CF_bf16 [384][2048]            1,572,864
#define OFF_CL    102275072u    // cl f32 [384][18]                  27,648
#define OFF_H     102302720u    // h_bf16 [384][1024]               786,432

// ---------- prep: Wb f32 -> bf16 (768 blocks exact) ----------
__global__ __launch_bounds__(256) void k_prepW(const float* __restrict__ Wb,
                                               unsigned short* __restrict__ Wbb) {
  int i = (blockIdx.x * 256 + threadIdx.x) * 8;   // n = 2048*768 = 1,572,864 exact
  fl4 v0 = *(const fl4*)(Wb + i);
  fl4 v1 = *(const fl4*)(Wb + i + 4);
  us8 o;
  o[0] = f2bf(v0[0]); o[1] = f2bf(v0[1]); o[2] = f2bf(v0[2]); o[3] = f2bf(v0[3]);
  o[4] = f2bf(v1[0]); o[5] = f2bf(v1[1]); o[6] = f2bf(v1[2]); o[7] = f2bf(v1[3]);
  *(us8*)(Wbb + i) = o;
}

// ---------- fused im2col + backbone GEMM + RoI-pool partials ----------
// A: reg-staged from fp32 img (im2col addressing), cvt once, ds_write bf16 (XOR-swz).
// B: global_load_lds from Wbb (linear). 2-barrier/K-step structure (m97-proven).
// Epilogue: relu(acc+bias) -> LDS fm-tile [c][p] (XOR-swz) -> per-block pool MFMA
// mask[32m x 128p] x fm[128p x 128c] -> CFpart[b][m][slice][c] f32 (no fmT in HBM).
__global__ __launch_bounds__(256) void k_gemm1fp(const float* __restrict__ img,
                                                 const unsigned short* __restrict__ BT,
                                                 const float* __restrict__ bias,
                                                 const float* __restrict__ masks,
                                                 float* __restrict__ CFpart) {
  __shared__ unsigned short smem[16384];    // 32KB: As2[128][64] 16K | Bs 16K ; pool: fmt[128][128]
  unsigned short* Bs = smem + 8192;
  int bid = blockIdx.x;                     // 2048 blocks
  int swz = (bid & 7) * 256 + (bid >> 3);   // bijective XCD swizzle (2048 % 8 == 0)
  int bm = swz >> 4, bn = swz & 15;
  int m0 = bm * 128, n0 = bn * 128;
  int t = threadIdx.x;
  int w = t >> 6, l = t & 63, lr = l & 15, lg = l >> 4;
  int wr = w >> 1, wc = w & 1;

  // A-staging invariants (same im2col math as validated round-5 kernel)
  int arow = t >> 1;                        // 0..127
  int am = m0 + arow;
  int ab = am >> 10, ap = am & 1023, ahf = ap >> 5, awf = ap & 31;
  const float* imb = img + ((size_t)(ab * 3) * 512 + (size_t)ahf * 16) * 512 + awf * 16;
  int kq = (t & 1) * 4;
  int awx = (arow & 7) << 4;                // write-side swizzle
  int arx = (lr & 7) << 4;                  // read-side swizzle

  f32x4 acc[4][4] = {};
  for (int k0 = 0; k0 < KDIM; k0 += 64) {
    // stage B (async, linear LDS dest)
#pragma unroll
    for (int g = 0; g < 4; ++g)
      GLOAD16(BT + (size_t)(n0 + (t >> 1)) * KDIM + k0 + g * 16 + (t & 1) * 8,
              Bs + g * 2048 + t * 8);
    // stage A: f32 load -> cvt -> swizzled bf16 ds_write
#pragma unroll
    for (int j = 0; j < 8; ++j) {
      int k = k0 + j * 8 + kq;
      int c = k >> 8, py = (k >> 4) & 15, px = k & 15;
      fl4 v = *(const fl4*)(imb + ((size_t)c * 512 + py) * 512 + px);
      us4 o;
      o[0] = f2bf_h(v[0]); o[1] = f2bf_h(v[1]); o[2] = f2bf_h(v[2]); o[3] = f2bf_h(v[3]);
      *(us4*)((char*)smem + ((arow * 128 + j * 16 + kq * 2) ^ awx)) = o;
    }
    __syncthreads();   // drains vmcnt (B) + lgkmcnt (A writes)
#pragma unroll
    for (int kk = 0; kk < 64; kk += 32) {
      bf16x8 a[4], bb[4];
#pragma unroll
      for (int mi = 0; mi < 4; ++mi) {
        int row = wr * 64 + mi * 16 + lr;
        a[mi] = *(const bf16x8*)((const char*)smem + ((row * 128 + kk * 2 + lg * 16) ^ arx));
      }
#pragma unroll
      for (int ni = 0; ni < 4; ++ni) {
        int row = wc * 64 + ni * 16 + lr;
        int g = (kk >> 4) + (lg >> 1), half = lg & 1;
        bb[ni] = *(const bf16x8*)(Bs + g * 2048 + row * 16 + half * 8);
      }
#pragma unroll
      for (int mi = 0; mi < 4; ++mi)
#pragma unroll
        for (int ni = 0; ni < 4; ++ni)
          acc[mi][ni] = mfma16(a[mi], bb[ni], acc[mi][ni]);
    }
    __syncthreads();
  }

  // ---- epilogue: relu(acc+bias) -> fmt LDS [c][p] (swizzled) ----
  int b = m0 >> 10;
  int p0 = m0 & 1023;
  int slice = (m0 >> 7) & 7;
  int pl0 = wr * 64 + lg * 4;
#pragma unroll
  for (int ni = 0; ni < 4; ++ni) {
    int gcol = n0 + wc * 64 + ni * 16 + lr;
    float bv = bias[gcol];
    int cl_ = wc * 64 + ni * 16 + lr;
    int cwx = (cl_ & 7) << 4;
#pragma unroll
    for (int mi = 0; mi < 4; ++mi) {
      us4 o;
#pragma unroll
      for (int r = 0; r < 4; ++r)
        o[r] = f2bf_h(fmaxf(acc[mi][ni][r] + bv, 0.f));
      *(us4*)((char*)smem + ((cl_ * 256 + (pl0 + mi * 16) * 2) ^ cwx)) = o;
    }
  }
  __syncthreads();

  // ---- pool MFMA: mask[32 x 128] x fmt[128 x 128c-slice] ----
  f32x4 pacc[2][2] = {};
#pragma unroll
  for (int ks = 0; ks < 4; ++ks) {
    int kb = ks * 32 + lg * 8;
    bf16x8 amk[2];
#pragma unroll
    for (int mt = 0; mt < 2; ++mt) {
      int mrow = mt * 16 + lr;
      us8 tmp = {};
      if (mrow < KCELL) {
        const float* mp = masks + ((size_t)(b * KCELL + mrow)) * P_ + p0 + kb;
        fl4 u0 = *(const fl4*)mp;
        fl4 u1 = *(const fl4*)(mp + 4);
        tmp[0] = f2bf_h(u0[0]); tmp[1] = f2bf_h(u0[1]); tmp[2] = f2bf_h(u0[2]); tmp[3] = f2bf_h(u0[3]);
        tmp[4] = f2bf_h(u1[0]); tmp[5] = f2bf_h(u1[1]); tmp[6] = f2bf_h(u1[2]); tmp[7] = f2bf_h(u1[3]);
      }
      amk[mt] = *(bf16x8*)&tmp;
    }
    bf16x8 bfv[2];
#pragma unroll
    for (int ct = 0; ct < 2; ++ct) {
      int cl2 = w * 32 + ct * 16 + lr;
      bfv[ct] = *(const bf16x8*)((const char*)smem + ((cl2 * 256 + kb * 2) ^ ((cl2 & 7) << 4)));
    }
    pacc[0][0] = mfma16(amk[0], bfv[0], pacc[0][0]);
    pacc[1][0] = mfma16(amk[1], bfv[0], pacc[1][0]);
    pacc[0][1] = mfma16(amk[0], bfv[1], pacc[0][1]);
    pacc[1][1] = mfma16(amk[1], bfv[1], pacc[1][1]);
  }
#pragma unroll
  for (int mt = 0; mt < 2; ++mt)
#pragma unroll
    for (int ct = 0; ct < 2; ++ct) {
      int cg = n0 + w * 32 + ct * 16 + lr;
#pragma unroll
      for (int r = 0; r < 4; ++r) {
        int m = mt * 16 + lg * 4 + r;
        if (m < KCELL)
          CFpart[(((size_t)(b * KCELL + m)) * 8 + slice) * C_FEAT + cg] = pacc[mt][ct][r];
      }
    }
}

// ---------- post: area + 8-slice reduce + /area + CF bf16 + class logits ----------
__global__ __launch_bounds__(256) void k_post(const float* __restrict__ masks,
                                              const float* __restrict__ CFpart,
                                              const float* __restrict__ Wf,
                                              const float* __restrict__ bfin,
                                              unsigned short* __restrict__ CF,
                                              float* __restrict__ cl) {
  int cell = blockIdx.x;      // 0..383
  int t = threadIdx.x;
  // area = sum(mask row) + EPS
  fl4 mv = *(const fl4*)(masks + (size_t)cell * P_ + t * 4);
  float s = mv[0] + mv[1] + mv[2] + mv[3];
  for (int off = 32; off; off >>= 1) s += __shfl_down(s, off);
  __shared__ float redA[4];
  __shared__ float red2[4][N_CLS];
  if ((t & 63) == 0) redA[t >> 6] = s;
  __syncthreads();
  float asum = redA[0] + redA[1] + redA[2] + redA[3];
  float ar = asum + EPS_;
  float inv = 1.f / ar;
  float coeff = asum / ar;
  // reduce 8 slices, scale, emit CF bf16
  int c0 = t * 8;
  float cf[8] = {};
#pragma unroll
  for (int s8 = 0; s8 < 8; ++s8) {
    const float* base = CFpart + ((size_t)cell * 8 + s8) * C_FEAT + c0;
    fl4 a = *(const fl4*)base;
    fl4 b = *(const fl4*)(base + 4);
    cf[0] += a[0]; cf[1] += a[1]; cf[2] += a[2]; cf[3] += a[3];
    cf[4] += b[0]; cf[5] += b[1]; cf[6] += b[2]; cf[7] += b[3];
  }
  us8 o;
#pragma unroll
  for (int j = 0; j < 8; ++j) { cf[j] *= inv; o[j] = f2bf(cf[j]); }
  *(us8*)(CF + (size_t)cell * C_FEAT + c0) = o;
  // class logits: acc[18] = dot(cf, Wf rows), block-reduce
  float acc[N_CLS];
#pragma unroll
  for (int oo = 0; oo < N_CLS; ++oo) {
    fl4 w0 = *(const fl4*)(Wf + (size_t)oo * C_FEAT + c0);
    fl4 w1 = *(const fl4*)(Wf + (size_t)oo * C_FEAT + c0 + 4);
    acc[oo] = cf[0]*w0[0] + cf[1]*w0[1] + cf[2]*w0[2] + cf[3]*w0[3]
            + cf[4]*w1[0] + cf[5]*w1[1] + cf[6]*w1[2] + cf[7]*w1[3];
  }
#pragma unroll
  for (int oo = 0; oo < N_CLS; ++oo)
    for (int off = 32; off; off >>= 1) acc[oo] += __shfl_down(acc[oo], off);
  if ((t & 63) == 0) {
#pragma unroll
    for (int oo = 0; oo < N_CLS; ++oo) red2[t >> 6][oo] = acc[oo];
  }
  __syncthreads();
  if (t < N_CLS)
    cl[(size_t)cell * N_CLS + t] =
        red2[0][t] + red2[1][t] + red2[2][t] + red2[3][t] + bfin[t] * coeff;
}

// ---------- MLP layer 1: h = relu(CF @ W1^T + b1), 16x16 wave tiles, W1 f32 direct ----------
__global__ __launch_bounds__(256) void k_mlp1(const unsigned short* __restrict__ CF,
                                              const float* __restrict__ W1,
                                              const float* __restrict__ b1,
                                              unsigned short* __restrict__ h) {
  int wid = blockIdx.x * 4 + (threadIdx.x >> 6);  // 0..1535
  int l = threadIdx.x & 63, lr = l & 15, lg = l >> 4;
  int mt = wid >> 6, nt = wid & 63;               // 24 x 64 tiles
  int m0 = mt * 16, n0 = nt * 16;
  f32x4 acc = {};
  for (int k0 = 0; k0 < C_FEAT; k0 += 32) {
    int kb = k0 + lg * 8;
    bf16x8 a = *(const bf16x8*)(CF + (size_t)(m0 + lr) * C_FEAT + kb);
    const float* wp = W1 + (size_t)(n0 + lr) * C_FEAT + kb;
    fl4 w0 = *(const fl4*)wp;
    fl4 w1 = *(const fl4*)(wp + 4);
    us8 bw;
    bw[0] = f2bf_h(w0[0]); bw[1] = f2bf_h(w0[1]); bw[2] = f2bf_h(w0[2]); bw[3] = f2bf_h(w0[3]);
    bw[4] = f2bf_h(w1[0]); bw[5] = f2bf_h(w1[1]); bw[6] = f2bf_h(w1[2]); bw[7] = f2bf_h(w1[3]);
    acc = mfma16(a, *(bf16x8*)&bw, acc);
  }
  int col = n0 + lr;
  float bv = b1[col];
#pragma unroll
  for (int r = 0; r < 4; ++r) {
    int row = m0 + lg * 4 + r;
    h[(size_t)row * 1024 + col] = f2bf(fmaxf(acc[r] + bv, 0.f));
  }
}

// ---------- MLP layer 2 + per-image softmax over cells + weighted sum (W2 f32) ----------
__global__ __launch_bounds__(512) void k_mlp2_final(const unsigned short* __restrict__ hbf,
                                                    const float* __restrict__ W2,
                                                    const float* __restrict__ b2,
                                                    const float* __restrict__ cl,
                                                    float* __restrict__ out) {
  int b = blockIdx.x;
  int t = threadIdx.x;
  __shared__ float wl[KCELL][N_CLS + 2];
  if (t < KCELL * N_CLS) {
    int k = t / N_CLS, o = t % N_CLS;
    const unsigned short* hr = hbf + (size_t)(b * KCELL + k) * 1024;
    const float* wr = W2 + (size_t)o * 1024;
    float acc = 0.f;
    for (int c = 0; c < 1024; c += 8) {
      bf16x8 hv = *(const bf16x8*)(hr + c);
      fl4 w0 = *(const fl4*)(wr + c);
      fl4 w1 = *(const fl4*)(wr + c + 4);
      acc += bf2f((unsigned short)hv[0]) * w0[0] + bf2f((unsigned short)hv[1]) * w0[1]
           + bf2f((unsigned short)hv[2]) * w0[2] + bf2f((unsigned short)hv[3]) * w0[3]
           + bf2f((unsigned short)hv[4]) * w1[0] + bf2f((unsigned short)hv[5]) * w1[1]
           + bf2f((unsigned short)hv[6]) * w1[2] + bf2f((unsigned short)hv[7]) * w1[3];
    }
    wl[k][o] = acc + b2[o];
  }
  __syncthreads();
  if (t < N_CLS) {
    float m = -3.4e38f;
    for (int k = 0; k < KCELL; ++k) m = fmaxf(m, wl[k][t]);
    float s = 0.f, num = 0.f;
    for (int k = 0; k < KCELL; ++k) {
      float e = expf(wl[k][t] - m);
      s += e;
      num += e * cl[(size_t)(b * KCELL + k) * N_CLS + t];
    }
    out[b * N_CLS + t] = num / s;
  }
}

// ---------- fallback (cell_counts==0): recompute class-map max from scratch ----------
// Cold path: never executes for benchmark inputs (counts==24); correctness-only.
__global__ __launch_bounds__(256) void k_fallback(const int* __restrict__ counts,
                                                  const float* __restrict__ img,
                                                  const float* __restrict__ Wb,
                                                  const float* __restrict__ bb,
                                                  const float* __restrict__ Wf,
                                                  const float* __restrict__ bfin,
                                                  float* __restrict__ out) {
  int b = blockIdx.x;
  if (counts[b] > 0) return;   // always taken for these inputs
  int t = threadIdx.x;
  float lmax[N_CLS];
#pragma unroll
  for (int o = 0; o < N_CLS; ++o) lmax[o] = -3.4e38f;
  for (int p = t; p < P_; p += 256) {
    int hfp = p >> 5, wfp = p & 31;
    const float* ib = img + ((size_t)(b * 3) * 512 + (size_t)hfp * 16) * 512 + wfp * 16;
    float accp[N_CLS];
#pragma unroll
    for (int o = 0; o < N_CLS; ++o) accp[o] = bfin[o];
    for (int c = 0; c < C_FEAT; ++c) {
      float f = bb[c];
      const float* wrow = Wb + (size_t)c * KDIM;
      for (int k = 0; k < KDIM; ++k) {
        int ci = k >> 8, py = (k >> 4) & 15, px = k & 15;
        f += wrow[k] * ib[((size_t)ci * 512 + py) * 512 + px];
      }
      f = fmaxf(f, 0.f);
      for (int o = 0; o < N_CLS; ++o) accp[o] += Wf[(size_t)o * C_FEAT + c] * f;
    }
#pragma unroll
    for (int o = 0; o < N_CLS; ++o) lmax[o] = fmaxf(lmax[o], accp[o]);
  }
#pragma unroll
  for (int o = 0; o < N_CLS; ++o)
    for (int off = 32; off; off >>= 1) lmax[o] = fmaxf(lmax[o], __shfl_down(lmax[o], off));
  __shared__ float red[4][N_CLS];
  if ((t & 63) == 0) {
#pragma unroll
    for (int o = 0; o < N_CLS; ++o) red[t >> 6][o] = lmax[o];
  }
  __syncthreads();
  if (t < N_CLS)
    out[b * N_CLS + t] = fmaxf(fmaxf(red[0][t], red[1][t]), fmaxf(red[2][t], red[3][t]));
}

// ---------- launch ----------
extern "C" void kernel_launch(void* const* d_in, const int* in_sizes, int n_in,
                              void* d_out, int out_size, void* d_ws, size_t ws_size,
                              hipStream_t stream) {
  const float* img    = (const float*)d_in[0];
  const float* masks  = (const float*)d_in[1];
  const int*   counts = (const int*)d_in[2];
  const float* Wb     = (const float*)d_in[3];
  const float* bb     = (const float*)d_in[4];
  const float* Wf     = (const float*)d_in[5];
  const float* bfin   = (const float*)d_in[6];
  const float* W1     = (const float*)d_in[7];
  const float* b1     = (const float*)d_in[8];
  const float* W2     = (const float*)d_in[9];
  const float* b2     = (const float*)d_in[10];
  float* out = (float*)d_out;

  char* ws = (char*)d_ws;
  float*          CFpart = (float*)(ws + OFF_CFP);
  unsigned short* Wbb    = (unsigned short*)(ws + OFF_WB);
  unsigned short* CF     = (unsigned short*)(ws + OFF_CF);
  float*          cl     = (float*)(ws + OFF_CL);
  unsigned short* hb     = (unsigned short*)(ws + OFF_H);

  // Wb -> bf16
  k_prepW<<<768, 256, 0, stream>>>(Wb, Wbb);
  // fused im2col + GEMM + pool partials (no fmT materialization)
  k_gemm1fp<<<2048, 256, 0, stream>>>(img, Wbb, bb, masks, CFpart);
  // reduce partials + area + CF bf16 + class logits
  k_post<<<B_ * KCELL, 256, 0, stream>>>(masks, CFpart, Wf, bfin, CF, cl);
  // MLP
  k_mlp1<<<(24 * 64) / 4, 256, 0, stream>>>(CF, W1, b1, hb);
  k_mlp2_final<<<B_, 512, 0, stream>>>(hb, W2, b2, cl, out);
  // zero-count fallback (early-exits when counts>0)
  k_fallback<<<B_, 256, 0, stream>>>(counts, img, Wb, bb, Wf, bfin, out);
}